// Round 3
// baseline (159.824 us; speedup 1.0000x reference)
//
#include <hip/hip_runtime.h>
#include <math.h>

// KAN layer forward, MI355X.
// NUM_IN = NUM_OUT = 128, SIZE = 16384, BATCH = 512, K = 3 (cubic), G = 5.
//
// Reference semantics:
//   s = o*128 + i ;  pre_acts[s,b]   = x[b,i]
//   post_splines[s,b] = mask[s] * sum_j coef[s,j] * B3_j(x[b,i]; grid_s)
//   post_acts[s,b]    = scale_b[s]*silu(x[b,i]) + scale_spline[s]*post_splines[s,b]
//   y[b,i] = sum_o post_acts[o*128+i, b]
// Outputs concatenated: y (512*128), pre_acts.T, post_splines.T, post_acts.T
// (each 512*16384, layout [b][s]).
//
// v3b: identical to v3 but the vector loads/stores use a native clang
// ext_vector_type(4) float ("f4") — __builtin_nontemporal_store rejects
// HIP's float4 class type. Goal codegen: global_store_dwordx4 ... nt.
//
// Structure: pure write-streaming kernel (~100 MB stores; ~1.3 MB param
// reads, L1/L2-resident). Thread owns 4 consecutive i -> float4-width NT
// stores on all three output streams; 8 o-slices per block reduced in LDS
// before y atomics; grid = 4096 blocks for full occupancy.

#define N_IN   128
#define SIZEK  16384

#define IT 4   // consecutive i per thread (dwordx4 store width)
#define TB 2   // batches per thread
#define OD 8   // o-slices per block

typedef float f4 __attribute__((ext_vector_type(4)));

__global__ __launch_bounds__(256) void kan_fwd(
    const float* __restrict__ x,            // [512][128]
    const float* __restrict__ scale_b,      // [16384]
    const float* __restrict__ scale_spline, // [16384]
    const float* __restrict__ coef,         // [16384][8]
    const float* __restrict__ mask,         // [16384]
    const float* __restrict__ knots,        // [16384][6]
    float* __restrict__ y,                  // [512][128] (pre-zeroed)
    float* __restrict__ pre_out,            // [512][16384]
    float* __restrict__ spl_out,            // [512][16384]
    float* __restrict__ post_out)           // [512][16384]
{
    const int tid = threadIdx.x;
    const int i4  = tid & 31;        // i-group (4 consecutive i)
    const int od  = tid >> 5;        // o-slice within block (0..7)
    const int og  = blockIdx.x & 15; // o-group (16 groups of 8)
    const int bg  = blockIdx.x >> 4; // batch-group (256 groups of 2)
    const int o   = (og << 3) | od;
    const int i0  = i4 << 2;
    const int b0  = bg << 1;
    const int s0  = (o << 7) | i0;   // 4 consecutive edges s0..s0+3

    // ---- per-edge params for the 4 consecutive s (independent loads)
    float e0v[IT], ihv[IT];
#pragma unroll
    for (int j = 0; j < IT; ++j) {
        const int s = s0 + j;
        const float k0 = knots[s * 6];
        const float k5 = knots[s * 6 + 5];
        const float h  = (k5 - k0) * 0.2f;   // (g_last-g_first)/G, G=5
        ihv[j] = 1.0f / h;
        e0v[j] = k0 - 3.0f * h;              // leftmost extended knot
    }
    const f4 mk4 = *(const f4*)(mask         + s0);
    const f4 sb4 = *(const f4*)(scale_b      + s0);
    const f4 ss4 = *(const f4*)(scale_spline + s0);

    f4 ysum[TB];
#pragma unroll
    for (int t = 0; t < TB; ++t) ysum[t] = (f4)(0.0f);

#pragma unroll
    for (int t = 0; t < TB; ++t) {
        const int b = b0 + t;
        const f4 xv = *(const f4*)(x + b * N_IN + i0);
        f4 sp4, po4;

#pragma unroll
        for (int ii = 0; ii < IT; ++ii) {
            const int s = s0 + ii;
            const float xx = xv[ii];
            const float u  = (xx - e0v[ii]) * ihv[ii];
            const float mf = floorf(u);
            const int   m  = (int)mf;
            const float tt = u - mf;                // fractional position
            const bool inr = (m >= 0) && (m <= 10); // inside extended grid?

            const float t2  = tt * tt;
            const float t3  = t2 * tt;
            const float omt = 1.0f - tt;
            float w[4];
            w[0] = omt * omt * omt * (1.0f / 6.0f);
            w[1] = (3.0f * t3 - 6.0f * t2 + 4.0f) * (1.0f / 6.0f);
            w[2] = (-3.0f * t3 + 3.0f * t2 + 3.0f * tt + 1.0f) * (1.0f / 6.0f);
            w[3] = t3 * (1.0f / 6.0f);

            const int jlo = m - 3;
            const float* __restrict__ cs = coef + (size_t)s * 8;
            float spline = 0.0f;
#pragma unroll
            for (int rr = 0; rr < 4; ++rr) {
                const int j  = jlo + rr;
                const int jc = min(max(j, 0), 7);   // clamp: keep load in-bounds
                const float c  = cs[jc];            // L1-resident gather
                const float wv = (inr && j >= 0 && j <= 7) ? w[rr] : 0.0f;
                spline = fmaf(c, wv, spline);
            }

            const float splm = spline * mk4[ii];
            const float sil  = xx / (1.0f + __expf(-xx)); // silu
            sp4[ii] = splm;
            po4[ii] = fmaf(sb4[ii], sil, ss4[ii] * splm);
        }

        const size_t idx = (size_t)b * SIZEK + (size_t)s0;
        __builtin_nontemporal_store(xv,  (f4*)(pre_out  + idx));
        __builtin_nontemporal_store(sp4, (f4*)(spl_out  + idx));
        __builtin_nontemporal_store(po4, (f4*)(post_out + idx));
        ysum[t] += po4;
    }

    // ---- reduce ysum across the 8 o-slices in LDS, then 4 atomics/lane
    __shared__ f4 red[OD][64];   // [od][(t<<5)|i4], 8 KB
#pragma unroll
    for (int t = 0; t < TB; ++t)
        red[od][(t << 5) | i4] = ysum[t];
    __syncthreads();

    if (tid < 64) {
        f4 a = red[0][tid];
#pragma unroll
        for (int d = 1; d < OD; ++d)
            a += red[d][tid];
        const int t  = tid >> 5;
        const int ig = tid & 31;
        float* yp = y + (b0 + t) * N_IN + (ig << 2);
        atomicAdd(yp + 0, a.x);
        atomicAdd(yp + 1, a.y);
        atomicAdd(yp + 2, a.z);
        atomicAdd(yp + 3, a.w);
    }
}

extern "C" void kernel_launch(void* const* d_in, const int* in_sizes, int n_in,
                              void* d_out, int out_size, void* d_ws, size_t ws_size,
                              hipStream_t stream) {
    const float* x            = (const float*)d_in[0];
    const float* scale_b      = (const float*)d_in[1];
    const float* scale_spline = (const float*)d_in[2];
    const float* coef         = (const float*)d_in[3];
    const float* mask         = (const float*)d_in[4];
    const float* knots        = (const float*)d_in[5];

    float* out  = (float*)d_out;
    float* y    = out;                         // 512*128      = 65536
    float* pre  = y + 512 * 128;               // 512*16384    = 8388608
    float* spl  = pre + (size_t)512 * 16384;
    float* post = spl + (size_t)512 * 16384;

    // y is accumulated with atomics; harness poisons d_out with 0xAA.
    (void)hipMemsetAsync(y, 0, 512 * 128 * sizeof(float), stream);

    // blocks: 16 o-groups x 256 batch-groups = 4096; 256 threads each.
    dim3 grid(4096), block(256);
    kan_fwd<<<grid, block, 0, stream>>>(x, scale_b, scale_spline, coef, mask,
                                        knots, y, pre, spl, post);
}

// Round 4
// 127.214 us; speedup vs baseline: 1.2563x; 1.2563x over previous
//
#include <hip/hip_runtime.h>
#include <math.h>

// KAN layer forward, MI355X.
// NUM_IN = NUM_OUT = 128, SIZE = 16384, BATCH = 512, K = 3 (cubic), G = 5.
//
// Reference semantics:
//   s = o*128 + i ;  pre_acts[s,b]   = x[b,i]
//   post_splines[s,b] = mask[s] * sum_j coef[s,j] * B3_j(x[b,i]; grid_s)
//   post_acts[s,b]    = scale_b[s]*silu(x[b,i]) + scale_spline[s]*post_splines[s,b]
//   y[b,i] = sum_o post_acts[o*128+i, b]
// Outputs concatenated: y (512*128), pre_acts.T, post_splines.T, post_acts.T
// (each 512*16384, layout [b][s]).
//
// v4 = v2 (the 129 us best-known: CO=4, 2048 blocks, scalar NT stores,
// prefetched params, silu amortized per batch) + ONE change:
//   - the coef window select is an explicit cndmask bit-tree over 8
//     register-resident coefficients instead of a runtime-indexed cf[8]
//     local array (dynamic indexing lowers to scratch) and instead of
//     v3b's per-lane global gathers (line-divergent gathers from rows
//     128 B apart choked the TA unit -> v3b regressed to ~2x v2).
//     Select stays in the VALU, which is only ~19% busy.

#define N_IN   128
#define SIZEK  16384
#define BATCH  512

#define TB 4    // batches per thread
#define CO 4    // o-values per thread

__global__ __launch_bounds__(256) void kan_fwd(
    const float* __restrict__ x,            // [512][128]
    const float* __restrict__ scale_b,      // [16384]
    const float* __restrict__ scale_spline, // [16384]
    const float* __restrict__ coef,         // [16384][8]
    const float* __restrict__ mask,         // [16384]
    const float* __restrict__ knots,        // [16384][6]
    float* __restrict__ y,                  // [512][128] (pre-zeroed)
    float* __restrict__ pre_out,            // [512][16384]
    float* __restrict__ spl_out,            // [512][16384]
    float* __restrict__ post_out)           // [512][16384]
{
    const int g  = blockIdx.x * blockDim.x + threadIdx.x;
    const int i  = g & 127;          // input index (lane-consecutive -> coalesced)
    const int r  = g >> 7;
    const int oc = r & 31;           // o-chunk id (32 chunks of 4)
    const int bg = r >> 5;           // batch-group id (128 groups of 4)
    const int o0 = oc << 2;
    const int b0 = bg << 2;

    float xv[TB], sil[TB], ysum[TB];
#pragma unroll
    for (int t = 0; t < TB; ++t) {
        const float xx = x[(b0 + t) * N_IN + i];
        xv[t]   = xx;
        sil[t]  = xx / (1.0f + __expf(-xx));   // silu(x) = x * sigmoid(x)
        ysum[t] = 0.0f;
    }

    // ---- prefetch all CO param rows (independent loads -> one waitcnt batch)
    float e0v[CO], ihv[CO], mkv[CO], sbv[CO], ssv[CO];
    float4 cA[CO], cB[CO];
#pragma unroll
    for (int oo = 0; oo < CO; ++oo) {
        const int s = ((o0 + oo) << 7) | i;
        const float k0 = knots[s * 6];
        const float k5 = knots[s * 6 + 5];
        const float h  = (k5 - k0) * 0.2f;     // (g_last-g_first)/G, G=5
        ihv[oo] = 1.0f / h;
        e0v[oo] = k0 - 3.0f * h;               // leftmost extended knot
        mkv[oo] = mask[s];
        sbv[oo] = scale_b[s];
        ssv[oo] = scale_spline[s];
        const float4* c4 = (const float4*)(coef + (size_t)s * 8);
        cA[oo] = c4[0];
        cB[oo] = c4[1];
    }

#pragma unroll
    for (int oo = 0; oo < CO; ++oo) {
        const int s = ((o0 + oo) << 7) | i;
        const float e0   = e0v[oo];
        const float invh = ihv[oo];
        const float mk   = mkv[oo];
        const float sb   = sbv[oo];
        const float ss   = ssv[oo];
        // 8 coefficients live in registers; selected via cndmask tree below.
        const float c0 = cA[oo].x, c1 = cA[oo].y, c2 = cA[oo].z, c3 = cA[oo].w;
        const float c4 = cB[oo].x, c5 = cB[oo].y, c6 = cB[oo].z, c7 = cB[oo].w;

#pragma unroll
        for (int t = 0; t < TB; ++t) {
            const float u  = (xv[t] - e0) * invh;
            const float mf = floorf(u);
            const int   m  = (int)mf;
            const float tt = u - mf;               // fractional position in interval
            const bool inr = (m >= 0) && (m <= 10); // inside extended grid?

            const float t2  = tt * tt;
            const float t3  = t2 * tt;
            const float omt = 1.0f - tt;
            float w[4];
            w[0] = omt * omt * omt * (1.0f / 6.0f);
            w[1] = (3.0f * t3 - 6.0f * t2 + 4.0f) * (1.0f / 6.0f);
            w[2] = (-3.0f * t3 + 3.0f * t2 + 3.0f * tt + 1.0f) * (1.0f / 6.0f);
            w[3] = t3 * (1.0f / 6.0f);

            const int jlo = m - 3;
            float spline = 0.0f;
#pragma unroll
            for (int rr = 0; rr < 4; ++rr) {
                const int j  = jlo + rr;
                const int jc = min(max(j, 0), 7);   // clamped select index
                // register-only 8->1 select by bits of jc (7 cndmask, no scratch)
                const float s01   = (jc & 1) ? c1 : c0;
                const float s23   = (jc & 1) ? c3 : c2;
                const float s45   = (jc & 1) ? c5 : c4;
                const float s67   = (jc & 1) ? c7 : c6;
                const float s0123 = (jc & 2) ? s23 : s01;
                const float s4567 = (jc & 2) ? s67 : s45;
                const float c     = (jc & 4) ? s4567 : s0123;
                const float wv = (inr && j >= 0 && j <= 7) ? w[rr] : 0.0f;
                spline = fmaf(c, wv, spline);
            }

            const float splm = spline * mk;
            const float post = fmaf(sb, sil[t], ss * splm);

            const size_t idx = (size_t)(b0 + t) * SIZEK + (size_t)s;
            __builtin_nontemporal_store(xv[t], &pre_out[idx]);
            __builtin_nontemporal_store(splm, &spl_out[idx]);
            __builtin_nontemporal_store(post, &post_out[idx]);
            ysum[t] += post;
        }
    }

#pragma unroll
    for (int t = 0; t < TB; ++t)
        atomicAdd(&y[(b0 + t) * N_IN + i], ysum[t]);
}

extern "C" void kernel_launch(void* const* d_in, const int* in_sizes, int n_in,
                              void* d_out, int out_size, void* d_ws, size_t ws_size,
                              hipStream_t stream) {
    const float* x            = (const float*)d_in[0];
    const float* scale_b      = (const float*)d_in[1];
    const float* scale_spline = (const float*)d_in[2];
    const float* coef         = (const float*)d_in[3];
    const float* mask         = (const float*)d_in[4];
    const float* knots        = (const float*)d_in[5];

    float* out  = (float*)d_out;
    float* y    = out;                         // 512*128      = 65536
    float* pre  = y + 512 * 128;               // 512*16384    = 8388608
    float* spl  = pre + (size_t)512 * 16384;
    float* post = spl + (size_t)512 * 16384;

    // y is accumulated with atomics; harness poisons d_out with 0xAA.
    (void)hipMemsetAsync(y, 0, 512 * 128 * sizeof(float), stream);

    // threads = 128 i * 32 o-chunks * 128 b-groups = 524288 -> 2048 blocks
    dim3 grid(2048), block(256);
    kan_fwd<<<grid, block, 0, stream>>>(x, scale_b, scale_spline, coef, mask,
                                        knots, y, pre, spl, post);
}